// Round 6
// baseline (352.470 us; speedup 1.0000x reference)
//
#include <hip/hip_runtime.h>
#include <hip/hip_bf16.h>
#include <math.h>

using bf16 = __hip_bfloat16;

static constexpr int Bn = 4;
static constexpr int Tn = 2048;
static constexpr int Dn = 1024;

typedef __attribute__((ext_vector_type(8))) short bf16x8;
typedef __attribute__((ext_vector_type(4))) float f32x4;

__device__ __forceinline__ float ldf(float v) { return v; }
__device__ __forceinline__ float ldf(bf16 v) { return __bfloat162float(v); }
__device__ __forceinline__ bf16 f2b(float v) { return __float2bfloat16(v); }
__device__ __forceinline__ float b2f(short s) {
    return __uint_as_float(((unsigned)(unsigned short)s) << 16);
}
__device__ __forceinline__ short f2bs(float v) {
    bf16 t = __float2bfloat16(v);
    return *reinterpret_cast<short*>(&t);
}

template <typename T> __device__ __forceinline__ T from_float(float v);
template <> __device__ __forceinline__ float from_float<float>(float v) { return v; }
template <> __device__ __forceinline__ bf16 from_float<bf16>(float v) { return f2b(v); }

__device__ __forceinline__ void load4(const float* p, float* v) {
    const float4 t = *(const float4*)p;
    v[0] = t.x; v[1] = t.y; v[2] = t.z; v[3] = t.w;
}
__device__ __forceinline__ void load4(const bf16* p, float* v) {
    const short4 t = *(const short4*)p;
    v[0] = b2f(t.x); v[1] = b2f(t.y); v[2] = b2f(t.z); v[3] = b2f(t.w);
}

// async global->LDS, 16B per lane; LDS dest wave-uniform base, HW scatters +lane*16.
__device__ __forceinline__ void async_copy16(const bf16* g, bf16* l) {
    __builtin_amdgcn_global_load_lds(
        (const __attribute__((address_space(1))) void*)g,
        (__attribute__((address_space(3))) void*)l,
        16, 0, 0);
}

// ---------------------------------------------------------------------------
// 8-phase-style 256xBN NT GEMM (bf16): C[m,n] = sum_k A[m,k]*B[n,k].
// T3+T4+T5 structure (verified rounds 1-5 on QK/V): raw s_barrier, counted
// vmcnt per K-tile (never 0 in main loop), setprio(1) around MFMA clusters,
// BK=32, 3-deep LDS ring.
// MODE 0: plain grid (bm, bn, bz).
// MODE 1: scores — grid (bn, bz, bm), causal skip bn>bm, full K.
// MODE 2: PV split-K2 — grid (bn, bz, zc): bm = 7-(zc>>1) (heavy-first),
//         chunk = zc&1, K-range = halves of [(0, (bm+1)*256).
// EPI 0: plain store (+optional bias / bf16 residual).
// EPI 1 (BN=128): V-transpose into vtp[b][d][t].
// EPI 2: masked exp scores + atomic rowsum.
// EPI 3: raw fp32 partial store to (chunk ? c2 : C).
// ---------------------------------------------------------------------------
template <int BN, int EPI, int MODE, typename OutT>
__global__ __launch_bounds__(512, 2) void gemm8p(
    const bf16* __restrict__ A, const bf16* __restrict__ Bm,
    OutT* __restrict__ C, float* __restrict__ c2,
    const float* __restrict__ bias, const bf16* __restrict__ res,
    bf16* __restrict__ vtp, float* __restrict__ rowsum,
    int K, int lda, int ldb, int ldc, long sA, long sB, long sC)
{
    static_assert(EPI != 1 || BN == 128, "V-transpose epilogue needs BN=128");
    constexpr int BM = 256, BK = 32;
    constexpr int NT = BN / 64;                   // per-wave 16-col fragments
    constexpr int BUFE = (BM + BN) * BK;          // elems per buffer
    __shared__ __align__(16) bf16 smem[3 * BUFE];

    int bm, bn, bz = 0, chunk = 0;
    if constexpr (MODE == 1) {
        bn = blockIdx.x; bz = blockIdx.y; bm = blockIdx.z;
        if (bn > bm) return;                       // causal block skip
    } else if constexpr (MODE == 2) {
        bn = blockIdx.x; bz = blockIdx.y;
        const int zc = blockIdx.z;
        bm = 7 - (zc >> 1);                        // heavy-first
        chunk = zc & 1;
    } else {
        bm = blockIdx.x; bn = blockIdx.y; bz = blockIdx.z;
    }

    int kbeg = 0, kmax = K;
    if constexpr (MODE == 2) {
        const int keff = (bm + 1) * BM;            // K truncated at diagonal
        const int half = keff >> 1;                // multiple of 128
        kbeg = chunk ? half : 0;
        kmax = chunk ? keff : half;
    }
    const int NK = (kmax - kbeg) >> 5;             // K-tiles of 32

    const bf16* Ab = A + (size_t)bz * sA;
    const bf16* Bb = Bm + (size_t)bz * sB;

    const int tid = threadIdx.x;
    const int wave = tid >> 6;
    const int lane = tid & 63;
    const int wm = wave >> 2;          // 0..1  (M direction, 128 rows each)
    const int wn = wave & 3;           // 0..3  (N direction, BN/4 cols each)
    const int lr = lane >> 2;          // staging: row within 16-row subtile
    const int lc = (lane & 3) * 8;     // staging: col (8 bf16 = 16B)
    const int arow = lane & 15;        // frag read: row within subtile
    const int kq = (lane >> 4) * 8;    // frag read: k-offset

    const bf16* gA0 = Ab + (size_t)(bm * BM + wave * 16 + lr) * lda + lc + kbeg;
    const bf16* gA1 = Ab + (size_t)(bm * BM + (wave + 8) * 16 + lr) * lda + lc + kbeg;
    const bf16* gB0 = Bb + (size_t)(bn * BN + wave * 16 + lr) * ldb + lc + kbeg;
    const bf16* gB1 = (BN == 256)
        ? Bb + (size_t)(bn * BN + (wave + 8) * 16 + lr) * ldb + lc + kbeg : nullptr;

    f32x4 acc[8][NT] = {};

    // ---- prologue: stage tiles 0 and 1, wait for tile 0 only ----
    {
        bf16* As0 = smem;               // buf 0
        bf16* Bs0 = smem + BM * BK;
        bf16* As1 = smem + BUFE;        // buf 1
        bf16* Bs1 = smem + BUFE + BM * BK;
        async_copy16(gA0, As0 + wave * 512);
        async_copy16(gA1, As0 + (wave + 8) * 512);
        async_copy16(gB0, Bs0 + wave * 512);
        if constexpr (BN == 256) async_copy16(gB1, Bs0 + (wave + 8) * 512);
        async_copy16(gA0 + BK, As1 + wave * 512);
        async_copy16(gA1 + BK, As1 + (wave + 8) * 512);
        async_copy16(gB0 + BK, Bs1 + wave * 512);
        if constexpr (BN == 256) async_copy16(gB1 + BK, Bs1 + (wave + 8) * 512);
    }
    if constexpr (BN == 256) asm volatile("s_waitcnt vmcnt(4)" ::: "memory");
    else                     asm volatile("s_waitcnt vmcnt(3)" ::: "memory");
    __builtin_amdgcn_s_barrier();

    int cb = 0;  // buffer holding current tile kt
    int sb = 2;  // buffer receiving tile kt+2
    for (int kt = 0; kt < NK; ++kt) {
        const bf16* As = smem + cb * BUFE;
        const bf16* Bs = As + BM * BK;
        const bool st = (kt + 2) < NK;
        const int koff = (kt + 2) * BK;

        // ============ phase 1: low half of N fragments ============
        bf16x8 af[8], bf0[NT / 2];
#pragma unroll
        for (int mt = 0; mt < 8; ++mt)
            af[mt] = *(const bf16x8*)&As[(wm * 8 + mt) * 512 + arow * 32 + kq];
#pragma unroll
        for (int nt = 0; nt < NT / 2; ++nt)
            bf0[nt] = *(const bf16x8*)&Bs[(wn * NT + nt) * 512 + arow * 32 + kq];
        if (st) {  // stage A half of tile kt+2
            bf16* Ad = smem + sb * BUFE;
            async_copy16(gA0 + koff, Ad + wave * 512);
            async_copy16(gA1 + koff, Ad + (wave + 8) * 512);
        }
        __builtin_amdgcn_s_barrier();
        asm volatile("s_waitcnt lgkmcnt(0)" ::: "memory");
        __builtin_amdgcn_sched_barrier(0);
        __builtin_amdgcn_s_setprio(1);
#pragma unroll
        for (int mt = 0; mt < 8; ++mt)
#pragma unroll
            for (int nt = 0; nt < NT / 2; ++nt)
                acc[mt][nt] = __builtin_amdgcn_mfma_f32_16x16x32_bf16(
                    af[mt], bf0[nt], acc[mt][nt], 0, 0, 0);
        __builtin_amdgcn_s_setprio(0);
        __builtin_amdgcn_s_barrier();

        // ============ phase 2: high half of N fragments ============
        bf16x8 bf1[NT / 2];
#pragma unroll
        for (int nt = 0; nt < NT / 2; ++nt)
            bf1[nt] = *(const bf16x8*)&Bs[(wn * NT + NT / 2 + nt) * 512 + arow * 32 + kq];
        if (st) {  // stage B half of tile kt+2
            bf16* Bd = smem + sb * BUFE + BM * BK;
            async_copy16(gB0 + koff, Bd + wave * 512);
            if constexpr (BN == 256) async_copy16(gB1 + koff, Bd + (wave + 8) * 512);
        }
        __builtin_amdgcn_s_barrier();
        asm volatile("s_waitcnt lgkmcnt(0)" ::: "memory");
        __builtin_amdgcn_sched_barrier(0);
        __builtin_amdgcn_s_setprio(1);
#pragma unroll
        for (int mt = 0; mt < 8; ++mt)
#pragma unroll
            for (int nt = 0; nt < NT / 2; ++nt)
                acc[mt][NT / 2 + nt] = __builtin_amdgcn_mfma_f32_16x16x32_bf16(
                    af[mt], bf1[nt], acc[mt][NT / 2 + nt], 0, 0, 0);
        __builtin_amdgcn_s_setprio(0);
        if (st) {
            if constexpr (BN == 256) asm volatile("s_waitcnt vmcnt(4)" ::: "memory");
            else                     asm volatile("s_waitcnt vmcnt(3)" ::: "memory");
        } else {
            asm volatile("s_waitcnt vmcnt(0)" ::: "memory");
        }
        __builtin_amdgcn_s_barrier();

        cb = (cb + 1 == 3) ? 0 : cb + 1;
        sb = (sb + 1 == 3) ? 0 : sb + 1;
    }

    const int qrow = (lane >> 4) * 4;
    const int ccol = lane & 15;
    const int row0 = bm * BM + wm * 128;
    const int col0 = bn * BN + wn * (NT * 16);

    if constexpr (EPI == 1) {
        // V-transpose: block output is 256(t) x 128(d); write vt[b][d][t].
        bf16* tt = smem;
#pragma unroll
        for (int mt = 0; mt < 8; ++mt)
#pragma unroll
            for (int nt = 0; nt < NT; ++nt) {
                const int dl = wn * (NT * 16) + nt * 16 + ccol;
                const int tl = wm * 128 + mt * 16 + qrow;
                short4 o;
                o.x = f2bs(acc[mt][nt][0]);
                o.y = f2bs(acc[mt][nt][1]);
                o.z = f2bs(acc[mt][nt][2]);
                o.w = f2bs(acc[mt][nt][3]);
                *(short4*)&tt[dl * 264 + tl] = o;
            }
        __syncthreads();
        const int b = (bm * BM) >> 11;
        const int tin = (bm * BM) & (Tn - 1);
        const int dr = tid >> 4;           // 0..31
        const int t0 = (tid & 15) * 16;    // 0..240
#pragma unroll
        for (int p = 0; p < 4; ++p) {
            const int d = p * 32 + dr;
            const bf16* srcl = &tt[d * 264 + t0];
            bf16* dst = vtp + ((size_t)b * Dn + bn * BN + d) * Tn + tin + t0;
            ((bf16x8*)dst)[0] = ((const bf16x8*)srcl)[0];
            ((bf16x8*)dst)[1] = ((const bf16x8*)srcl)[1];
        }
        return;
    }

    if constexpr (EPI == 2) {
        // masked exp scores + atomic row sums (of the bf16-rounded values)
        OutT* Cb = C + (size_t)bz * sC;
        float* rsb = rowsum + (size_t)bz * Tn;
        const float scale = 0.03125f;
#pragma unroll
        for (int mt = 0; mt < 8; ++mt) {
            float rsv[4] = {0.f, 0.f, 0.f, 0.f};
#pragma unroll
            for (int nt = 0; nt < NT; ++nt) {
                const int cc = col0 + nt * 16 + ccol;
#pragma unroll
                for (int r = 0; r < 4; ++r) {
                    const int rr = row0 + mt * 16 + qrow + r;
                    float e = 0.0f;
                    if (cc <= rr) {
                        const short es = f2bs(__expf(acc[mt][nt][r] * scale));
                        Cb[(size_t)rr * ldc + cc] = *(const bf16*)&es;
                        e = b2f(es);
                    } else {
                        Cb[(size_t)rr * ldc + cc] = from_float<OutT>(0.0f);
                    }
                    rsv[r] += e;
                }
            }
#pragma unroll
            for (int r = 0; r < 4; ++r) {
                float v = rsv[r];
                v += __shfl_xor(v, 1);
                v += __shfl_xor(v, 2);
                v += __shfl_xor(v, 4);
                v += __shfl_xor(v, 8);
                if (ccol == 0)
                    atomicAdd(rsb + row0 + mt * 16 + qrow + r, v);
            }
        }
        return;
    }

    if constexpr (EPI == 3) {
        // raw fp32 partial store (PV split-K2)
        float* Cb = (chunk ? c2 : (float*)C) + (size_t)bz * sC;
#pragma unroll
        for (int mt = 0; mt < 8; ++mt)
#pragma unroll
            for (int nt = 0; nt < NT; ++nt) {
                const int cc = col0 + nt * 16 + ccol;
#pragma unroll
                for (int r = 0; r < 4; ++r) {
                    const int rr = row0 + mt * 16 + qrow + r;
                    Cb[(size_t)rr * ldc + cc] = acc[mt][nt][r];
                }
            }
        return;
    }

    // EPI 0: plain epilogue (+bias, optional bf16 residual)
#pragma unroll
    for (int mt = 0; mt < 8; ++mt)
#pragma unroll
        for (int nt = 0; nt < NT; ++nt) {
            const int cc = col0 + nt * 16 + ccol;
            const float bv = bias ? bias[cc] : 0.0f;
#pragma unroll
            for (int r = 0; r < 4; ++r) {
                const int rr = row0 + mt * 16 + qrow + r;
                float v = acc[mt][nt][r] + bv;
                if (res) v += b2f(*(const short*)&res[(size_t)rr * ldc + cc]);
                C[(size_t)rr * ldc + cc] = from_float<OutT>(v);
            }
        }
}

// ---------------------------------------------------------------------------
// Generic NT GEMM (2-barrier 128x128 structure) — MLP1/MLP2 only (mode 0).
// ---------------------------------------------------------------------------
template <int BM, int BN, int MINW, int EPI, typename OutT, typename ResT, bool RELU>
__global__ __launch_bounds__(256, MINW) void gemm_nt(
    const bf16* __restrict__ A, const bf16* __restrict__ Bm,
    OutT* __restrict__ C, const float* __restrict__ bias,
    const ResT* __restrict__ res,
    int M, int N, int K, int lda, int ldb, int ldc)
{
    const int bm = blockIdx.x, bn = blockIdx.y;

    constexpr int WROWS = BM / 64;
    constexpr int WCOLS = 4 / WROWS;
    constexpr int TM = 64;
    constexpr int TN = BN / WCOLS;
    constexpr int MT = TM / 16;
    constexpr int NT = TN / 16;
    constexpr int nA = BM / 16;
    constexpr int nB = BN / 16;
    constexpr int STAGE = 2 * (BM + BN) * 32;

    __shared__ __align__(16) bf16 smem[STAGE];
    bf16* As = smem;
    bf16* Bs = smem + 2 * BM * 32;

    const int tid = threadIdx.x;
    const int wave = tid >> 6;
    const int lane = tid & 63;
    const int wm = wave / WCOLS;
    const int wn = wave % WCOLS;

    f32x4 acc[MT][NT] = {};

    const int lr = lane >> 2;
    const int lc = (lane & 3) * 8;
    const bf16* gAc[nA / 4]; bf16* lAc[nA / 4];
    const bf16* gBc[nB / 4]; bf16* lBc[nB / 4];
#pragma unroll
    for (int i = 0; i < nA / 4; ++i) {
        const int c = wave + 4 * i;
        gAc[i] = A + (size_t)(bm * BM + c * 16 + lr) * lda + lc;
        lAc[i] = &As[c * 512];
    }
#pragma unroll
    for (int i = 0; i < nB / 4; ++i) {
        const int c = wave + 4 * i;
        gBc[i] = Bm + (size_t)(bn * BN + c * 16 + lr) * ldb + lc;
        lBc[i] = &Bs[c * 512];
    }

    const int arow = lane & 15;
    const int kq = (lane >> 4) * 8;

    for (int k0 = 0; k0 < K; k0 += 64) {
#pragma unroll
        for (int hh = 0; hh < 2; ++hh) {
#pragma unroll
            for (int i = 0; i < nA / 4; ++i)
                async_copy16(gAc[i] + k0 + 32 * hh, lAc[i] + hh * (BM * 32));
#pragma unroll
            for (int i = 0; i < nB / 4; ++i)
                async_copy16(gBc[i] + k0 + 32 * hh, lBc[i] + hh * (BN * 32));
        }
        __syncthreads();

#pragma unroll
        for (int hh = 0; hh < 2; ++hh) {
            const bf16* Ah = As + hh * (BM * 32);
            const bf16* Bh = Bs + hh * (BN * 32);
            bf16x8 af[MT], bfm[NT];
#pragma unroll
            for (int t = 0; t < MT; ++t)
                af[t] = *(const bf16x8*)&Ah[(wm * TM + t * 16 + arow) * 32 + kq];
#pragma unroll
            for (int t = 0; t < NT; ++t)
                bfm[t] = *(const bf16x8*)&Bh[(wn * TN + t * 16 + arow) * 32 + kq];
#pragma unroll
            for (int mt = 0; mt < MT; ++mt)
#pragma unroll
                for (int nt = 0; nt < NT; ++nt)
                    acc[mt][nt] = __builtin_amdgcn_mfma_f32_16x16x32_bf16(
                        af[mt], bfm[nt], acc[mt][nt], 0, 0, 0);
        }
        __syncthreads();
    }

    const int rowBase = bm * BM + wm * TM;
    const int colBase = bn * BN + wn * TN;
    const int qrow = (lane >> 4) * 4;
    const int ccol = lane & 15;

#pragma unroll
    for (int mt = 0; mt < MT; ++mt) {
#pragma unroll
        for (int nt = 0; nt < NT; ++nt) {
            const int cc = colBase + nt * 16 + ccol;
            const float bv = bias ? bias[cc] : 0.0f;
#pragma unroll
            for (int r = 0; r < 4; ++r) {
                const int rr = rowBase + mt * 16 + qrow + r;
                float v = acc[mt][nt][r] + bv;
                if (RELU) v = fmaxf(v, 0.0f);
                if (res) v += ldf(res[(size_t)rr * ldc + cc]);
                C[(size_t)rr * ldc + cc] = from_float<OutT>(v);
            }
        }
    }
}

// ---------------------------------------------------------------------------
// LayerNorm body (faithfully buggy): out = (x - mean/sqrt(var_unbiased))*g + b
// ---------------------------------------------------------------------------
template <typename InT>
__device__ __forceinline__ void ln_row(
    const InT* __restrict__ xr, const float* __restrict__ gamma,
    const float* __restrict__ beta, bf16* __restrict__ orow, int tid)
{
    const int j = tid * 4;
    float v[4];
    load4(xr + j, v);
    float s = v[0] + v[1] + v[2] + v[3];
    float sq = v[0] * v[0] + v[1] * v[1] + v[2] * v[2] + v[3] * v[3];
#pragma unroll
    for (int o = 32; o > 0; o >>= 1) {
        s += __shfl_down(s, o);
        sq += __shfl_down(sq, o);
    }
    __shared__ float red[2][4];
    const int lane = tid & 63, w = tid >> 6;
    if (lane == 0) { red[0][w] = s; red[1][w] = sq; }
    __syncthreads();
    s  = red[0][0] + red[0][1] + red[0][2] + red[0][3];
    sq = red[1][0] + red[1][1] + red[1][2] + red[1][3];
    const float mean = s / (float)Dn;
    const float var = (sq - s * s / (float)Dn) / (float)(Dn - 1);
    const float coef = mean * rsqrtf(var);

    const float4 g = *(const float4*)(gamma + j);
    const float4 be = *(const float4*)(beta + j);
    short4 o;
    o.x = f2bs((v[0] - coef) * g.x + be.x);
    o.y = f2bs((v[1] - coef) * g.y + be.y);
    o.z = f2bs((v[2] - coef) * g.z + be.z);
    o.w = f2bs((v[3] - coef) * g.w + be.w);
    *(short4*)(orow + j) = o;
}

// ---------------------------------------------------------------------------
// Fused PV-merge + LN2: y = (p0 + p1)/rowsum + x (fp32), write y (bf16) and
// h2 = LN(y).
// ---------------------------------------------------------------------------
__global__ __launch_bounds__(256) void ln2_fused(
    const float* __restrict__ yp0, const float* __restrict__ yp1,
    const float* __restrict__ rowsum, const float* __restrict__ x,
    const float* __restrict__ gamma, const float* __restrict__ beta,
    bf16* __restrict__ y, bf16* __restrict__ h2)
{
    const int row = blockIdx.x;
    const int tid = threadIdx.x;
    const int j = tid * 4;
    const size_t base = (size_t)row * Dn;
    const float inv = 1.0f / rowsum[row];

    float p0[4], p1[4], xv[4], v[4];
    load4(yp0 + base + j, p0);
    load4(yp1 + base + j, p1);
    load4(x + base + j, xv);
    short4 yo;
    v[0] = (p0[0] + p1[0]) * inv + xv[0];
    v[1] = (p0[1] + p1[1]) * inv + xv[1];
    v[2] = (p0[2] + p1[2]) * inv + xv[2];
    v[3] = (p0[3] + p1[3]) * inv + xv[3];
    yo.x = f2bs(v[0]); yo.y = f2bs(v[1]); yo.z = f2bs(v[2]); yo.w = f2bs(v[3]);
    *(short4*)(y + base + j) = yo;

    float s = v[0] + v[1] + v[2] + v[3];
    float sq = v[0] * v[0] + v[1] * v[1] + v[2] * v[2] + v[3] * v[3];
#pragma unroll
    for (int o = 32; o > 0; o >>= 1) {
        s += __shfl_down(s, o);
        sq += __shfl_down(sq, o);
    }
    __shared__ float red[2][4];
    const int lane = tid & 63, w = tid >> 6;
    if (lane == 0) { red[0][w] = s; red[1][w] = sq; }
    __syncthreads();
    s  = red[0][0] + red[0][1] + red[0][2] + red[0][3];
    sq = red[1][0] + red[1][1] + red[1][2] + red[1][3];
    const float mean = s / (float)Dn;
    const float var = (sq - s * s / (float)Dn) / (float)(Dn - 1);
    const float coef = mean * rsqrtf(var);

    const float4 g = *(const float4*)(gamma + j);
    const float4 be = *(const float4*)(beta + j);
    short4 o;
    o.x = f2bs((v[0] - coef) * g.x + be.x);
    o.y = f2bs((v[1] - coef) * g.y + be.y);
    o.z = f2bs((v[2] - coef) * g.z + be.z);
    o.w = f2bs((v[3] - coef) * g.w + be.w);
    *(short4*)(h2 + base + j) = o;
}

// ---------------------------------------------------------------------------
// Fused prep: [0,5120) weight transposes (5 x 1024^2, fp32->bf16),
// [5120,5128) zero rowsum, [5128,13320) LN1 rows.
// ---------------------------------------------------------------------------
struct WPtrs { const float* p[5]; };

__global__ __launch_bounds__(256) void prep_kernel(
    WPtrs wp, bf16* __restrict__ wdst, float* __restrict__ rowsum,
    const float* __restrict__ x, const float* __restrict__ gamma1,
    const float* __restrict__ beta1, bf16* __restrict__ h)
{
    const int bx = blockIdx.x;
    if (bx < 5120) {
        __shared__ bf16 tile[32][33];
        const int z = bx >> 10;
        const int t = bx & 1023;
        const float* src = wp.p[z];
        bf16* d = wdst + (size_t)z * Dn * Dn;
        const int c0 = (t & 31) * 32, r0 = (t >> 5) * 32;
        const int tx = threadIdx.x & 31;
        const int ty = threadIdx.x >> 5;
#pragma unroll
        for (int dy = 0; dy < 32; dy += 8)
            tile[ty + dy][tx] = f2b(src[(size_t)(r0 + ty + dy) * Dn + (c0 + tx)]);
        __syncthreads();
#pragma unroll
        for (int dy = 0; dy < 32; dy += 8)
            d[(size_t)(c0 + ty + dy) * Dn + (r0 + tx)] = tile[tx][ty + dy];
    } else if (bx < 5128) {
        const int base = (bx - 5120) * 1024;
#pragma unroll
        for (int i = 0; i < 4; ++i) rowsum[base + i * 256 + threadIdx.x] = 0.0f;
    } else {
        const int row = bx - 5128;
        ln_row(x + (size_t)row * Dn, gamma1, beta1, h + (size_t)row * Dn, threadIdx.x);
    }
}

extern "C" void kernel_launch(void* const* d_in, const int* in_sizes, int n_in,
                              void* d_out, int out_size, void* d_ws, size_t ws_size,
                              hipStream_t stream) {
    const float* x      = (const float*)d_in[0];
    const float* gamma1 = (const float*)d_in[1];
    const float* beta1  = (const float*)d_in[2];
    const float* w_q    = (const float*)d_in[3];
    const float* w_k    = (const float*)d_in[4];
    const float* w_v    = (const float*)d_in[5];
    const float* gamma2 = (const float*)d_in[6];
    const float* beta2  = (const float*)d_in[7];
    const float* W1     = (const float*)d_in[8];
    const float* b1     = (const float*)d_in[9];
    const float* W2     = (const float*)d_in[10];
    const float* b2     = (const float*)d_in[11];
    float* out = (float*)d_out;   // fp32 output buffer (compared in bf16 space)

    char* ws = (char*)d_ws;
    size_t off = 0;
    auto alloc = [&](size_t bytes) {
        char* p = ws + off;
        off += (bytes + 255) & ~(size_t)255;
        return p;
    };
    const size_t BT = (size_t)Bn * Tn;
    bf16* h    = (bf16*)alloc(BT * Dn * 2);               // 16 MB; reused as h2
    bf16* qk   = (bf16*)alloc(BT * 2 * Dn * 2);           // 32 MB [8192,2048] (q|k)
    bf16* vt   = (bf16*)alloc(BT * Dn * 2);               // 16 MB [4][1024,2048]
    bf16* wbuf = (bf16*)alloc((size_t)5 * Dn * Dn * 2);   // 10 MB (wq|wk|wv|w1|w2)^T
    bf16* S    = (bf16*)alloc((size_t)Bn * Tn * Tn * 2);  // 32 MB masked exp scores
    bf16* y    = (bf16*)alloc(BT * Dn * 2);               // 16 MB
    float* rowsum = (float*)alloc((size_t)Bn * Tn * 4);   // 32 KB
    float* yp1 = (float*)alloc(BT * Dn * 4);              // 32 MB PV partial (chunk 1)
    float* yp0 = (float*)qk;   // 32 MB PV partial (chunk 0) — qk dead after scores
    bf16* h2   = h;            // h dead after QKV
    bf16* mid  = qk;           // qk dead after ln2_fused consumed yp0

    const dim3 blk(256);
    const dim3 blk512(512);
    const long TD  = (long)Tn * Dn;
    const long TT  = (long)Tn * Tn;
    const long TD2 = (long)Tn * 2 * Dn;
    const size_t DD = (size_t)Dn * Dn;

    // fused: 5 weight transposes + rowsum zero + LN1
    WPtrs wp; wp.p[0] = w_q; wp.p[1] = w_k; wp.p[2] = w_v; wp.p[3] = W1; wp.p[4] = W2;
    prep_kernel<<<dim3(5128 + (unsigned)BT, 1, 1), blk, 0, stream>>>(
        wp, wbuf, rowsum, x, gamma1, beta1, h);

    // qk = h @ [wq|wk]^T : 8-phase 256^2, grid 32x8 = 256 blocks (1/CU)
    gemm8p<256, 0, 0, bf16><<<dim3(32, 8, 1), blk512, 0, stream>>>(
        h, wbuf, qk, nullptr, nullptr, nullptr, nullptr, nullptr,
        Dn, Dn, Dn, 2 * Dn, 0, 0, 0);

    // vt[b][d][t] = (h @ wv^T)^T : 8-phase 256x128 + LDS-transpose epilogue
    gemm8p<128, 1, 0, bf16><<<dim3(32, 8, 1), blk512, 0, stream>>>(
        h, wbuf + 2 * DD, (bf16*)nullptr, nullptr, nullptr, nullptr, vt, nullptr,
        Dn, Dn, Dn, 0, 0, 0, 0);

    // S_exp = exp(q @ k^T * scale) causal-masked + atomic rowsum
    // 8-phase 256^2, grid (bn=8, bz=4, bm=8), 144 live blocks
    gemm8p<256, 2, 1, bf16><<<dim3(8, Bn, 8), blk512, 0, stream>>>(
        qk, qk + 1024, S, nullptr, nullptr, nullptr, nullptr, rowsum,
        Dn, 2 * Dn, 2 * Dn, Tn, TD2, TD2, TT);

    // PV split-K2: 8-phase 256^2, grid (bn=4, bz=4, zc=16) = 256 blocks (1/CU),
    // heavy-first; fp32 partials chunk0 -> yp0 (over qk), chunk1 -> yp1
    gemm8p<256, 3, 2, float><<<dim3(4, Bn, 16), blk512, 0, stream>>>(
        S, vt, yp0, yp1, nullptr, nullptr, nullptr, nullptr,
        Tn, Tn, Tn, Dn, TT, TD, TD);

    // fused merge + LN2: y = (yp0+yp1)/rowsum + x ; h2 = LN(y)
    ln2_fused<<<dim3((unsigned)BT), blk, 0, stream>>>(
        yp0, yp1, rowsum, x, gamma2, beta2, y, h2);

    // mid = relu(h2 @ W1 + b1)
    gemm_nt<128, 128, 4, 0, bf16, float, true><<<dim3(64, 8, 1), blk, 0, stream>>>(
        h2, wbuf + 3 * DD, mid, b1, nullptr,
        (int)BT, Dn, Dn, Dn, Dn, Dn);

    // out = mid @ W2 + b2 + y (fp32 out, bf16 residual)
    gemm_nt<128, 128, 4, 0, float, bf16, false><<<dim3(64, 8, 1), blk, 0, stream>>>(
        mid, wbuf + 4 * DD, out, b2, y,
        (int)BT, Dn, Dn, Dn, Dn, Dn);
}

// Round 7
// 337.576 us; speedup vs baseline: 1.0441x; 1.0441x over previous
//
#include <hip/hip_runtime.h>
#include <hip/hip_bf16.h>
#include <math.h>

using bf16 = __hip_bfloat16;

static constexpr int Bn = 4;
static constexpr int Tn = 2048;
static constexpr int Dn = 1024;

typedef __attribute__((ext_vector_type(8))) short bf16x8;
typedef __attribute__((ext_vector_type(4))) float f32x4;

__device__ __forceinline__ float ldf(float v) { return v; }
__device__ __forceinline__ float ldf(bf16 v) { return __bfloat162float(v); }
__device__ __forceinline__ bf16 f2b(float v) { return __float2bfloat16(v); }
__device__ __forceinline__ float b2f(short s) {
    return __uint_as_float(((unsigned)(unsigned short)s) << 16);
}
__device__ __forceinline__ short f2bs(float v) {
    bf16 t = __float2bfloat16(v);
    return *reinterpret_cast<short*>(&t);
}

template <typename T> __device__ __forceinline__ T from_float(float v);
template <> __device__ __forceinline__ float from_float<float>(float v) { return v; }
template <> __device__ __forceinline__ bf16 from_float<bf16>(float v) { return f2b(v); }

__device__ __forceinline__ void load4(const float* p, float* v) {
    const float4 t = *(const float4*)p;
    v[0] = t.x; v[1] = t.y; v[2] = t.z; v[3] = t.w;
}
__device__ __forceinline__ void load4(const bf16* p, float* v) {
    const short4 t = *(const short4*)p;
    v[0] = b2f(t.x); v[1] = b2f(t.y); v[2] = b2f(t.z); v[3] = b2f(t.w);
}

// async global->LDS, 16B per lane; LDS dest wave-uniform base, HW scatters +lane*16.
__device__ __forceinline__ void async_copy16(const bf16* g, bf16* l) {
    __builtin_amdgcn_global_load_lds(
        (const __attribute__((address_space(1))) void*)g,
        (__attribute__((address_space(3))) void*)l,
        16, 0, 0);
}

// T2 bank-conflict swizzle (st_16x32 analog for 16x32-elem bf16 subtiles):
// physical LDS byte = logical ^ ((logical>>9 & 1) << 5) within each 1 KiB
// subtile. global_load_lds writes linearly -> pre-swizzle the GLOBAL source
// column (lanes >= 32 swap col-chunks 0<->2, 1<->3); frag reads XOR the 32B
// bit for subtile-rows >= 8. Both sides are the same involution (rule #21).
//   store side: lc  = ((lane&3) ^ ((lane>>5)<<1)) * 8
//   read side:  kq  = ((lane>>4)*8) ^ ((lane&8)<<1)
// Reduces the frag-read ds_read_b128 aliasing from 8-way to 4-way.

// ---------------------------------------------------------------------------
// 8-phase-style 256xBN NT GEMM (bf16): C[m,n] = sum_k A[m,k]*B[n,k].
// T3+T4+T5 structure: raw s_barrier, counted vmcnt per K-tile (never 0 in
// main loop), setprio(1) around MFMA clusters, BK=32, 3-deep LDS ring.
// + T2 LDS swizzle (this round).
// MODE 0: plain grid (bm, bn, bz).
// MODE 1: scores — grid (bn, bz, bm), causal skip bn>bm, full K.
// MODE 2: PV split-K2 — grid (bn, bz, zc): bm = 7-(zc>>1) (heavy-first),
//         chunk = zc&1, K-range = halves of [0, (bm+1)*256).
// EPI 0: plain store (+optional bias / bf16 residual).
// EPI 1 (BN=128): V-transpose into vtp[b][d][t].
// EPI 2: masked exp scores + atomic rowsum.
// EPI 3: raw fp32 partial store to (chunk ? c2 : C).
// ---------------------------------------------------------------------------
template <int BN, int EPI, int MODE, typename OutT>
__global__ __launch_bounds__(512, 2) void gemm8p(
    const bf16* __restrict__ A, const bf16* __restrict__ Bm,
    OutT* __restrict__ C, float* __restrict__ c2,
    const float* __restrict__ bias, const bf16* __restrict__ res,
    bf16* __restrict__ vtp, float* __restrict__ rowsum,
    int K, int lda, int ldb, int ldc, long sA, long sB, long sC)
{
    static_assert(EPI != 1 || BN == 128, "V-transpose epilogue needs BN=128");
    constexpr int BM = 256, BK = 32;
    constexpr int NT = BN / 64;                   // per-wave 16-col fragments
    constexpr int BUFE = (BM + BN) * BK;          // elems per buffer
    __shared__ __align__(16) bf16 smem[3 * BUFE];

    int bm, bn, bz = 0, chunk = 0;
    if constexpr (MODE == 1) {
        bn = blockIdx.x; bz = blockIdx.y; bm = blockIdx.z;
        if (bn > bm) return;                       // causal block skip
    } else if constexpr (MODE == 2) {
        bn = blockIdx.x; bz = blockIdx.y;
        const int zc = blockIdx.z;
        bm = 7 - (zc >> 1);                        // heavy-first
        chunk = zc & 1;
    } else {
        bm = blockIdx.x; bn = blockIdx.y; bz = blockIdx.z;
    }

    int kbeg = 0, kmax = K;
    if constexpr (MODE == 2) {
        const int keff = (bm + 1) * BM;            // K truncated at diagonal
        const int half = keff >> 1;                // multiple of 128
        kbeg = chunk ? half : 0;
        kmax = chunk ? keff : half;
    }
    const int NK = (kmax - kbeg) >> 5;             // K-tiles of 32

    const bf16* Ab = A + (size_t)bz * sA;
    const bf16* Bb = Bm + (size_t)bz * sB;

    const int tid = threadIdx.x;
    const int wave = tid >> 6;
    const int lane = tid & 63;
    const int wm = wave >> 2;          // 0..1  (M direction, 128 rows each)
    const int wn = wave & 3;           // 0..3  (N direction, BN/4 cols each)
    const int lr = lane >> 2;          // staging: row within 16-row subtile
    const int lc = ((lane & 3) ^ ((lane >> 5) << 1)) * 8;  // T2 pre-swizzled col
    const int arow = lane & 15;        // frag read: row within subtile
    const int kq = ((lane >> 4) * 8) ^ ((lane & 8) << 1);  // T2 swizzled k-offset

    const bf16* gA0 = Ab + (size_t)(bm * BM + wave * 16 + lr) * lda + lc + kbeg;
    const bf16* gA1 = Ab + (size_t)(bm * BM + (wave + 8) * 16 + lr) * lda + lc + kbeg;
    const bf16* gB0 = Bb + (size_t)(bn * BN + wave * 16 + lr) * ldb + lc + kbeg;
    const bf16* gB1 = (BN == 256)
        ? Bb + (size_t)(bn * BN + (wave + 8) * 16 + lr) * ldb + lc + kbeg : nullptr;

    f32x4 acc[8][NT] = {};

    // ---- prologue: stage tiles 0 and 1, wait for tile 0 only ----
    {
        bf16* As0 = smem;               // buf 0
        bf16* Bs0 = smem + BM * BK;
        bf16* As1 = smem + BUFE;        // buf 1
        bf16* Bs1 = smem + BUFE + BM * BK;
        async_copy16(gA0, As0 + wave * 512);
        async_copy16(gA1, As0 + (wave + 8) * 512);
        async_copy16(gB0, Bs0 + wave * 512);
        if constexpr (BN == 256) async_copy16(gB1, Bs0 + (wave + 8) * 512);
        async_copy16(gA0 + BK, As1 + wave * 512);
        async_copy16(gA1 + BK, As1 + (wave + 8) * 512);
        async_copy16(gB0 + BK, Bs1 + wave * 512);
        if constexpr (BN == 256) async_copy16(gB1 + BK, Bs1 + (wave + 8) * 512);
    }
    if constexpr (BN == 256) asm volatile("s_waitcnt vmcnt(4)" ::: "memory");
    else                     asm volatile("s_waitcnt vmcnt(3)" ::: "memory");
    __builtin_amdgcn_s_barrier();

    int cb = 0;  // buffer holding current tile kt
    int sb = 2;  // buffer receiving tile kt+2
    for (int kt = 0; kt < NK; ++kt) {
        const bf16* As = smem + cb * BUFE;
        const bf16* Bs = As + BM * BK;
        const bool st = (kt + 2) < NK;
        const int koff = (kt + 2) * BK;

        // ============ phase 1: low half of N fragments ============
        bf16x8 af[8], bf0[NT / 2];
#pragma unroll
        for (int mt = 0; mt < 8; ++mt)
            af[mt] = *(const bf16x8*)&As[(wm * 8 + mt) * 512 + arow * 32 + kq];
#pragma unroll
        for (int nt = 0; nt < NT / 2; ++nt)
            bf0[nt] = *(const bf16x8*)&Bs[(wn * NT + nt) * 512 + arow * 32 + kq];
        if (st) {  // stage A half of tile kt+2
            bf16* Ad = smem + sb * BUFE;
            async_copy16(gA0 + koff, Ad + wave * 512);
            async_copy16(gA1 + koff, Ad + (wave + 8) * 512);
        }
        __builtin_amdgcn_s_barrier();
        asm volatile("s_waitcnt lgkmcnt(0)" ::: "memory");
        __builtin_amdgcn_sched_barrier(0);
        __builtin_amdgcn_s_setprio(1);
#pragma unroll
        for (int mt = 0; mt < 8; ++mt)
#pragma unroll
            for (int nt = 0; nt < NT / 2; ++nt)
                acc[mt][nt] = __builtin_amdgcn_mfma_f32_16x16x32_bf16(
                    af[mt], bf0[nt], acc[mt][nt], 0, 0, 0);
        __builtin_amdgcn_s_setprio(0);
        __builtin_amdgcn_s_barrier();

        // ============ phase 2: high half of N fragments ============
        bf16x8 bf1[NT / 2];
#pragma unroll
        for (int nt = 0; nt < NT / 2; ++nt)
            bf1[nt] = *(const bf16x8*)&Bs[(wn * NT + NT / 2 + nt) * 512 + arow * 32 + kq];
        if (st) {  // stage B half of tile kt+2
            bf16* Bd = smem + sb * BUFE + BM * BK;
            async_copy16(gB0 + koff, Bd + wave * 512);
            if constexpr (BN == 256) async_copy16(gB1 + koff, Bd + (wave + 8) * 512);
        }
        __builtin_amdgcn_s_barrier();
        asm volatile("s_waitcnt lgkmcnt(0)" ::: "memory");
        __builtin_amdgcn_sched_barrier(0);
        __builtin_amdgcn_s_setprio(1);
#pragma unroll
        for (int mt = 0; mt < 8; ++mt)
#pragma unroll
            for (int nt = 0; nt < NT / 2; ++nt)
                acc[mt][NT / 2 + nt] = __builtin_amdgcn_mfma_f32_16x16x32_bf16(
                    af[mt], bf1[nt], acc[mt][NT / 2 + nt], 0, 0, 0);
        __builtin_amdgcn_s_setprio(0);
        if (st) {
            if constexpr (BN == 256) asm volatile("s_waitcnt vmcnt(4)" ::: "memory");
            else                     asm volatile("s_waitcnt vmcnt(3)" ::: "memory");
        } else {
            asm volatile("s_waitcnt vmcnt(0)" ::: "memory");
        }
        __builtin_amdgcn_s_barrier();

        cb = (cb + 1 == 3) ? 0 : cb + 1;
        sb = (sb + 1 == 3) ? 0 : sb + 1;
    }

    const int qrow = (lane >> 4) * 4;
    const int ccol = lane & 15;
    const int row0 = bm * BM + wm * 128;
    const int col0 = bn * BN + wn * (NT * 16);

    if constexpr (EPI == 1) {
        // V-transpose: block output is 256(t) x 128(d); write vt[b][d][t].
        bf16* tt = smem;
#pragma unroll
        for (int mt = 0; mt < 8; ++mt)
#pragma unroll
            for (int nt = 0; nt < NT; ++nt) {
                const int dl = wn * (NT * 16) + nt * 16 + ccol;
                const int tl = wm * 128 + mt * 16 + qrow;
                short4 o;
                o.x = f2bs(acc[mt][nt][0]);
                o.y = f2bs(acc[mt][nt][1]);
                o.z = f2bs(acc[mt][nt][2]);
                o.w = f2bs(acc[mt][nt][3]);
                *(short4*)&tt[dl * 264 + tl] = o;
            }
        __syncthreads();
        const int b = (bm * BM) >> 11;
        const int tin = (bm * BM) & (Tn - 1);
        const int dr = tid >> 4;           // 0..31
        const int t0 = (tid & 15) * 16;    // 0..240
#pragma unroll
        for (int p = 0; p < 4; ++p) {
            const int d = p * 32 + dr;
            const bf16* srcl = &tt[d * 264 + t0];
            bf16* dst = vtp + ((size_t)b * Dn + bn * BN + d) * Tn + tin + t0;
            ((bf16x8*)dst)[0] = ((const bf16x8*)srcl)[0];
            ((bf16x8*)dst)[1] = ((const bf16x8*)srcl)[1];
        }
        return;
    }

    if constexpr (EPI == 2) {
        // masked exp scores + atomic row sums (of the bf16-rounded values)
        OutT* Cb = C + (size_t)bz * sC;
        float* rsb = rowsum + (size_t)bz * Tn;
        const float scale = 0.03125f;
#pragma unroll
        for (int mt = 0; mt < 8; ++mt) {
            float rsv[4] = {0.f, 0.f, 0.f, 0.f};
#pragma unroll
            for (int nt = 0; nt < NT; ++nt) {
                const int cc = col0 + nt * 16 + ccol;
#pragma unroll
                for (int r = 0; r < 4; ++r) {
                    const int rr = row0 + mt * 16 + qrow + r;
                    float e = 0.0f;
                    if (cc <= rr) {
                        const short es = f2bs(__expf(acc[mt][nt][r] * scale));
                        Cb[(size_t)rr * ldc + cc] = *(const bf16*)&es;
                        e = b2f(es);
                    } else {
                        Cb[(size_t)rr * ldc + cc] = from_float<OutT>(0.0f);
                    }
                    rsv[r] += e;
                }
            }
#pragma unroll
            for (int r = 0; r < 4; ++r) {
                float v = rsv[r];
                v += __shfl_xor(v, 1);
                v += __shfl_xor(v, 2);
                v += __shfl_xor(v, 4);
                v += __shfl_xor(v, 8);
                if (ccol == 0)
                    atomicAdd(rsb + row0 + mt * 16 + qrow + r, v);
            }
        }
        return;
    }

    if constexpr (EPI == 3) {
        // raw fp32 partial store (PV split-K2)
        float* Cb = (chunk ? c2 : (float*)C) + (size_t)bz * sC;
#pragma unroll
        for (int mt = 0; mt < 8; ++mt)
#pragma unroll
            for (int nt = 0; nt < NT; ++nt) {
                const int cc = col0 + nt * 16 + ccol;
#pragma unroll
                for (int r = 0; r < 4; ++r) {
                    const int rr = row0 + mt * 16 + qrow + r;
                    Cb[(size_t)rr * ldc + cc] = acc[mt][nt][r];
                }
            }
        return;
    }

    // EPI 0: plain epilogue (+bias, optional bf16 residual)
#pragma unroll
    for (int mt = 0; mt < 8; ++mt)
#pragma unroll
        for (int nt = 0; nt < NT; ++nt) {
            const int cc = col0 + nt * 16 + ccol;
            const float bv = bias ? bias[cc] : 0.0f;
#pragma unroll
            for (int r = 0; r < 4; ++r) {
                const int rr = row0 + mt * 16 + qrow + r;
                float v = acc[mt][nt][r] + bv;
                if (res) v += b2f(*(const short*)&res[(size_t)rr * ldc + cc]);
                C[(size_t)rr * ldc + cc] = from_float<OutT>(v);
            }
        }
}

// ---------------------------------------------------------------------------
// Generic NT GEMM (2-barrier 128x128 structure) — MLP1/MLP2 only.
// T2 swizzle applied here too (conflict-free reads; timing expected ~null at
// 2-phase per the regime gate, but it's free).
// ---------------------------------------------------------------------------
template <int BM, int BN, int MINW, int EPI, typename OutT, typename ResT, bool RELU>
__global__ __launch_bounds__(256, MINW) void gemm_nt(
    const bf16* __restrict__ A, const bf16* __restrict__ Bm,
    OutT* __restrict__ C, const float* __restrict__ bias,
    const ResT* __restrict__ res,
    int M, int N, int K, int lda, int ldb, int ldc)
{
    const int bm = blockIdx.x, bn = blockIdx.y;

    constexpr int WROWS = BM / 64;
    constexpr int WCOLS = 4 / WROWS;
    constexpr int TM = 64;
    constexpr int TN = BN / WCOLS;
    constexpr int MT = TM / 16;
    constexpr int NT = TN / 16;
    constexpr int nA = BM / 16;
    constexpr int nB = BN / 16;
    constexpr int STAGE = 2 * (BM + BN) * 32;

    __shared__ __align__(16) bf16 smem[STAGE];
    bf16* As = smem;
    bf16* Bs = smem + 2 * BM * 32;

    const int tid = threadIdx.x;
    const int wave = tid >> 6;
    const int lane = tid & 63;
    const int wm = wave / WCOLS;
    const int wn = wave % WCOLS;

    f32x4 acc[MT][NT] = {};

    const int lr = lane >> 2;
    const int lc = ((lane & 3) ^ ((lane >> 5) << 1)) * 8;  // T2 pre-swizzled col
    const bf16* gAc[nA / 4]; bf16* lAc[nA / 4];
    const bf16* gBc[nB / 4]; bf16* lBc[nB / 4];
#pragma unroll
    for (int i = 0; i < nA / 4; ++i) {
        const int c = wave + 4 * i;
        gAc[i] = A + (size_t)(bm * BM + c * 16 + lr) * lda + lc;
        lAc[i] = &As[c * 512];
    }
#pragma unroll
    for (int i = 0; i < nB / 4; ++i) {
        const int c = wave + 4 * i;
        gBc[i] = Bm + (size_t)(bn * BN + c * 16 + lr) * ldb + lc;
        lBc[i] = &Bs[c * 512];
    }

    const int arow = lane & 15;
    const int kq = ((lane >> 4) * 8) ^ ((lane & 8) << 1);  // T2 swizzled k-offset

    for (int k0 = 0; k0 < K; k0 += 64) {
#pragma unroll
        for (int hh = 0; hh < 2; ++hh) {
#pragma unroll
            for (int i = 0; i < nA / 4; ++i)
                async_copy16(gAc[i] + k0 + 32 * hh, lAc[i] + hh * (BM * 32));
#pragma unroll
            for (int i = 0; i < nB / 4; ++i)
                async_copy16(gBc[i] + k0 + 32 * hh, lBc[i] + hh * (BN * 32));
        }
        __syncthreads();

#pragma unroll
        for (int hh = 0; hh < 2; ++hh) {
            const bf16* Ah = As + hh * (BM * 32);
            const bf16* Bh = Bs + hh * (BN * 32);
            bf16x8 af[MT], bfm[NT];
#pragma unroll
            for (int t = 0; t < MT; ++t)
                af[t] = *(const bf16x8*)&Ah[(wm * TM + t * 16 + arow) * 32 + kq];
#pragma unroll
            for (int t = 0; t < NT; ++t)
                bfm[t] = *(const bf16x8*)&Bh[(wn * TN + t * 16 + arow) * 32 + kq];
#pragma unroll
            for (int mt = 0; mt < MT; ++mt)
#pragma unroll
                for (int nt = 0; nt < NT; ++nt)
                    acc[mt][nt] = __builtin_amdgcn_mfma_f32_16x16x32_bf16(
                        af[mt], bfm[nt], acc[mt][nt], 0, 0, 0);
        }
        __syncthreads();
    }

    const int rowBase = bm * BM + wm * TM;
    const int colBase = bn * BN + wn * TN;
    const int qrow = (lane >> 4) * 4;
    const int ccol = lane & 15;

#pragma unroll
    for (int mt = 0; mt < MT; ++mt) {
#pragma unroll
        for (int nt = 0; nt < NT; ++nt) {
            const int cc = colBase + nt * 16 + ccol;
            const float bv = bias ? bias[cc] : 0.0f;
#pragma unroll
            for (int r = 0; r < 4; ++r) {
                const int rr = rowBase + mt * 16 + qrow + r;
                float v = acc[mt][nt][r] + bv;
                if (RELU) v = fmaxf(v, 0.0f);
                if (res) v += ldf(res[(size_t)rr * ldc + cc]);
                C[(size_t)rr * ldc + cc] = from_float<OutT>(v);
            }
        }
    }
}

// ---------------------------------------------------------------------------
// LayerNorm body (faithfully buggy): out = (x - mean/sqrt(var_unbiased))*g + b
// ---------------------------------------------------------------------------
template <typename InT>
__device__ __forceinline__ void ln_row(
    const InT* __restrict__ xr, const float* __restrict__ gamma,
    const float* __restrict__ beta, bf16* __restrict__ orow, int tid)
{
    const int j = tid * 4;
    float v[4];
    load4(xr + j, v);
    float s = v[0] + v[1] + v[2] + v[3];
    float sq = v[0] * v[0] + v[1] * v[1] + v[2] * v[2] + v[3] * v[3];
#pragma unroll
    for (int o = 32; o > 0; o >>= 1) {
        s += __shfl_down(s, o);
        sq += __shfl_down(sq, o);
    }
    __shared__ float red[2][4];
    const int lane = tid & 63, w = tid >> 6;
    if (lane == 0) { red[0][w] = s; red[1][w] = sq; }
    __syncthreads();
    s  = red[0][0] + red[0][1] + red[0][2] + red[0][3];
    sq = red[1][0] + red[1][1] + red[1][2] + red[1][3];
    const float mean = s / (float)Dn;
    const float var = (sq - s * s / (float)Dn) / (float)(Dn - 1);
    const float coef = mean * rsqrtf(var);

    const float4 g = *(const float4*)(gamma + j);
    const float4 be = *(const float4*)(beta + j);
    short4 o;
    o.x = f2bs((v[0] - coef) * g.x + be.x);
    o.y = f2bs((v[1] - coef) * g.y + be.y);
    o.z = f2bs((v[2] - coef) * g.z + be.z);
    o.w = f2bs((v[3] - coef) * g.w + be.w);
    *(short4*)(orow + j) = o;
}

// ---------------------------------------------------------------------------
// Fused PV-merge + LN2: y = (p0 + p1)/rowsum + x (fp32), write y (bf16) and
// h2 = LN(y).
// ---------------------------------------------------------------------------
__global__ __launch_bounds__(256) void ln2_fused(
    const float* __restrict__ yp0, const float* __restrict__ yp1,
    const float* __restrict__ rowsum, const float* __restrict__ x,
    const float* __restrict__ gamma, const float* __restrict__ beta,
    bf16* __restrict__ y, bf16* __restrict__ h2)
{
    const int row = blockIdx.x;
    const int tid = threadIdx.x;
    const int j = tid * 4;
    const size_t base = (size_t)row * Dn;
    const float inv = 1.0f / rowsum[row];

    float p0[4], p1[4], xv[4], v[4];
    load4(yp0 + base + j, p0);
    load4(yp1 + base + j, p1);
    load4(x + base + j, xv);
    short4 yo;
    v[0] = (p0[0] + p1[0]) * inv + xv[0];
    v[1] = (p0[1] + p1[1]) * inv + xv[1];
    v[2] = (p0[2] + p1[2]) * inv + xv[2];
    v[3] = (p0[3] + p1[3]) * inv + xv[3];
    yo.x = f2bs(v[0]); yo.y = f2bs(v[1]); yo.z = f2bs(v[2]); yo.w = f2bs(v[3]);
    *(short4*)(y + base + j) = yo;

    float s = v[0] + v[1] + v[2] + v[3];
    float sq = v[0] * v[0] + v[1] * v[1] + v[2] * v[2] + v[3] * v[3];
#pragma unroll
    for (int o = 32; o > 0; o >>= 1) {
        s += __shfl_down(s, o);
        sq += __shfl_down(sq, o);
    }
    __shared__ float red[2][4];
    const int lane = tid & 63, w = tid >> 6;
    if (lane == 0) { red[0][w] = s; red[1][w] = sq; }
    __syncthreads();
    s  = red[0][0] + red[0][1] + red[0][2] + red[0][3];
    sq = red[1][0] + red[1][1] + red[1][2] + red[1][3];
    const float mean = s / (float)Dn;
    const float var = (sq - s * s / (float)Dn) / (float)(Dn - 1);
    const float coef = mean * rsqrtf(var);

    const float4 g = *(const float4*)(gamma + j);
    const float4 be = *(const float4*)(beta + j);
    short4 o;
    o.x = f2bs((v[0] - coef) * g.x + be.x);
    o.y = f2bs((v[1] - coef) * g.y + be.y);
    o.z = f2bs((v[2] - coef) * g.z + be.z);
    o.w = f2bs((v[3] - coef) * g.w + be.w);
    *(short4*)(h2 + base + j) = o;
}

// ---------------------------------------------------------------------------
// Fused prep: [0,5120) weight transposes (5 x 1024^2, fp32->bf16),
// [5120,5128) zero rowsum, [5128,13320) LN1 rows.
// ---------------------------------------------------------------------------
struct WPtrs { const float* p[5]; };

__global__ __launch_bounds__(256) void prep_kernel(
    WPtrs wp, bf16* __restrict__ wdst, float* __restrict__ rowsum,
    const float* __restrict__ x, const float* __restrict__ gamma1,
    const float* __restrict__ beta1, bf16* __restrict__ h)
{
    const int bx = blockIdx.x;
    if (bx < 5120) {
        __shared__ bf16 tile[32][33];
        const int z = bx >> 10;
        const int t = bx & 1023;
        const float* src = wp.p[z];
        bf16* d = wdst + (size_t)z * Dn * Dn;
        const int c0 = (t & 31) * 32, r0 = (t >> 5) * 32;
        const int tx = threadIdx.x & 31;
        const int ty = threadIdx.x >> 5;
#pragma unroll
        for (int dy = 0; dy < 32; dy += 8)
            tile[ty + dy][tx] = f2b(src[(size_t)(r0 + ty + dy) * Dn + (c0 + tx)]);
        __syncthreads();
#pragma unroll
        for (int dy = 0; dy < 32; dy += 8)
            d[(size_t)(c0 + ty + dy) * Dn + (r0 + tx)] = tile[tx][ty + dy];
    } else if (bx < 5128) {
        const int base = (bx - 5120) * 1024;
#pragma unroll
        for (int i = 0; i < 4; ++i) rowsum[base + i * 256 + threadIdx.x] = 0.0f;
    } else {
        const int row = bx - 5128;
        ln_row(x + (size_t)row * Dn, gamma1, beta1, h + (size_t)row * Dn, threadIdx.x);
    }
}

extern "C" void kernel_launch(void* const* d_in, const int* in_sizes, int n_in,
                              void* d_out, int out_size, void* d_ws, size_t ws_size,
                              hipStream_t stream) {
    const float* x      = (const float*)d_in[0];
    const float* gamma1 = (const float*)d_in[1];
    const float* beta1  = (const float*)d_in[2];
    const float* w_q    = (const float*)d_in[3];
    const float* w_k    = (const float*)d_in[4];
    const float* w_v    = (const float*)d_in[5];
    const float* gamma2 = (const float*)d_in[6];
    const float* beta2  = (const float*)d_in[7];
    const float* W1     = (const float*)d_in[8];
    const float* b1     = (const float*)d_in[9];
    const float* W2     = (const float*)d_in[10];
    const float* b2     = (const float*)d_in[11];
    float* out = (float*)d_out;   // fp32 output buffer (compared in bf16 space)

    char* ws = (char*)d_ws;
    size_t off = 0;
    auto alloc = [&](size_t bytes) {
        char* p = ws + off;
        off += (bytes + 255) & ~(size_t)255;
        return p;
    };
    const size_t BT = (size_t)Bn * Tn;
    bf16* h    = (bf16*)alloc(BT * Dn * 2);               // 16 MB; reused as h2
    bf16* qk   = (bf16*)alloc(BT * 2 * Dn * 2);           // 32 MB [8192,2048] (q|k)
    bf16* vt   = (bf16*)alloc(BT * Dn * 2);               // 16 MB [4][1024,2048]
    bf16* wbuf = (bf16*)alloc((size_t)5 * Dn * Dn * 2);   // 10 MB (wq|wk|wv|w1|w2)^T
    bf16* S    = (bf16*)alloc((size_t)Bn * Tn * Tn * 2);  // 32 MB masked exp scores
    bf16* y    = (bf16*)alloc(BT * Dn * 2);               // 16 MB
    float* rowsum = (float*)alloc((size_t)Bn * Tn * 4);   // 32 KB
    float* yp1 = (float*)alloc(BT * Dn * 4);              // 32 MB PV partial (chunk 1)
    float* yp0 = (float*)qk;   // 32 MB PV partial (chunk 0) — qk dead after scores
    bf16* h2   = h;            // h dead after QKV
    bf16* mid  = qk;           // qk dead after ln2_fused consumed yp0

    const dim3 blk(256);
    const dim3 blk512(512);
    const long TD  = (long)Tn * Dn;
    const long TT  = (long)Tn * Tn;
    const long TD2 = (long)Tn * 2 * Dn;
    const size_t DD = (size_t)Dn * Dn;

    // fused: 5 weight transposes + rowsum zero + LN1
    WPtrs wp; wp.p[0] = w_q; wp.p[1] = w_k; wp.p[2] = w_v; wp.p[3] = W1; wp.p[4] = W2;
    prep_kernel<<<dim3(5128 + (unsigned)BT, 1, 1), blk, 0, stream>>>(
        wp, wbuf, rowsum, x, gamma1, beta1, h);

    // qk = h @ [wq|wk]^T : 8-phase 256^2, grid 32x8 = 256 blocks (1/CU)
    gemm8p<256, 0, 0, bf16><<<dim3(32, 8, 1), blk512, 0, stream>>>(
        h, wbuf, qk, nullptr, nullptr, nullptr, nullptr, nullptr,
        Dn, Dn, Dn, 2 * Dn, 0, 0, 0);

    // vt[b][d][t] = (h @ wv^T)^T : 8-phase 256x128 + LDS-transpose epilogue
    gemm8p<128, 1, 0, bf16><<<dim3(32, 8, 1), blk512, 0, stream>>>(
        h, wbuf + 2 * DD, (bf16*)nullptr, nullptr, nullptr, nullptr, vt, nullptr,
        Dn, Dn, Dn, 0, 0, 0, 0);

    // S_exp = exp(q @ k^T * scale) causal-masked + atomic rowsum
    // 8-phase 256^2, grid (bn=8, bz=4, bm=8), 144 live blocks
    gemm8p<256, 2, 1, bf16><<<dim3(8, Bn, 8), blk512, 0, stream>>>(
        qk, qk + 1024, S, nullptr, nullptr, nullptr, nullptr, rowsum,
        Dn, 2 * Dn, 2 * Dn, Tn, TD2, TD2, TT);

    // PV split-K2: 8-phase 256^2, grid (bn=4, bz=4, zc=16) = 256 blocks (1/CU),
    // heavy-first; fp32 partials chunk0 -> yp0 (over qk), chunk1 -> yp1
    gemm8p<256, 3, 2, float><<<dim3(4, Bn, 16), blk512, 0, stream>>>(
        S, vt, yp0, yp1, nullptr, nullptr, nullptr, nullptr,
        Tn, Tn, Tn, Dn, TT, TD, TD);

    // fused merge + LN2: y = (yp0+yp1)/rowsum + x ; h2 = LN(y)
    ln2_fused<<<dim3((unsigned)BT), blk, 0, stream>>>(
        yp0, yp1, rowsum, x, gamma2, beta2, y, h2);

    // mid = relu(h2 @ W1 + b1)
    gemm_nt<128, 128, 4, 0, bf16, float, true><<<dim3(64, 8, 1), blk, 0, stream>>>(
        h2, wbuf + 3 * DD, mid, b1, nullptr,
        (int)BT, Dn, Dn, Dn, Dn, Dn);

    // out = mid @ W2 + b2 + y (fp32 out, bf16 residual)
    gemm_nt<128, 128, 4, 0, float, bf16, false><<<dim3(64, 8, 1), blk, 0, stream>>>(
        mid, wbuf + 4 * DD, out, b2, y,
        (int)BT, Dn, Dn, Dn, Dn, Dn);
}

// Round 8
// 333.319 us; speedup vs baseline: 1.0575x; 1.0128x over previous
//
#include <hip/hip_runtime.h>
#include <hip/hip_bf16.h>
#include <math.h>

using bf16 = __hip_bfloat16;

static constexpr int Bn = 4;
static constexpr int Tn = 2048;
static constexpr int Dn = 1024;

typedef __attribute__((ext_vector_type(8))) short bf16x8;
typedef __attribute__((ext_vector_type(4))) float f32x4;

__device__ __forceinline__ float ldf(float v) { return v; }
__device__ __forceinline__ float ldf(bf16 v) { return __bfloat162float(v); }
__device__ __forceinline__ bf16 f2b(float v) { return __float2bfloat16(v); }
__device__ __forceinline__ float b2f(short s) {
    return __uint_as_float(((unsigned)(unsigned short)s) << 16);
}
__device__ __forceinline__ short f2bs(float v) {
    bf16 t = __float2bfloat16(v);
    return *reinterpret_cast<short*>(&t);
}

template <typename T> __device__ __forceinline__ T from_float(float v);
template <> __device__ __forceinline__ float from_float<float>(float v) { return v; }
template <> __device__ __forceinline__ bf16 from_float<bf16>(float v) { return f2b(v); }

__device__ __forceinline__ void load4(const float* p, float* v) {
    const float4 t = *(const float4*)p;
    v[0] = t.x; v[1] = t.y; v[2] = t.z; v[3] = t.w;
}
__device__ __forceinline__ void load4(const bf16* p, float* v) {
    const short4 t = *(const short4*)p;
    v[0] = b2f(t.x); v[1] = b2f(t.y); v[2] = b2f(t.z); v[3] = b2f(t.w);
}

// async global->LDS, 16B per lane; LDS dest wave-uniform base, HW scatters +lane*16.
__device__ __forceinline__ void async_copy16(const bf16* g, bf16* l) {
    __builtin_amdgcn_global_load_lds(
        (const __attribute__((address_space(1))) void*)g,
        (__attribute__((address_space(3))) void*)l,
        16, 0, 0);
}

// T2 bank-conflict swizzle (verified round 7: SQ_LDS_BANK_CONFLICT 1.77M -> 0):
//   store side: lc = ((lane&3) ^ ((lane>>5)<<1)) * 8   (pre-swizzled global col)
//   read side:  kq = ((lane>>4)*8) ^ ((lane&8)<<1)
// Both sides the same involution (rule #21).

// PV split-K chunk tables (MODE 2): per (bn,bz) 16 chunks, all K%64==0,
// max chunk 768 (vs 1024 before) -> makespan -25%. Heavy-first in zc.
// zbm: row-block; zj: partial index (0..2); zk0/zk1: K range in 64-units.
__device__ __constant__ int zbm_t[16] = {7,7,5,5,4,4,6,6,6,7,3,3,1,2,2,0};
__device__ __constant__ int zj_t [16] = {0,1,0,1,0,1,0,1,2,2,0,1,0,0,1,0};
__device__ __constant__ int zk0_t[16] = {0,12,0,12,0,10,0,10,19,24,0,8,0,0,6,0};
__device__ __constant__ int zk1_t[16] = {12,24,12,24,10,20,10,19,28,32,8,16,8,6,12,4};

// ---------------------------------------------------------------------------
// 8-phase-style 256xBN NT GEMM (bf16): C[m,n] = sum_k A[m,k]*B[n,k].
// T3+T4+T5 structure + T2 swizzle. BK=32, 3-deep LDS ring, counted vmcnt.
// MODE 0: plain grid (bm, bn, bz).
// MODE 1: scores — grid (bn, bz, bm), causal skip bn>bm, full K.
// MODE 2: PV split-K — grid (bn, bz, zc): chunk tables above; bf16 partial
//         j written to {C, c2, vtp}[j].
// EPI 0: plain store (+optional bias / bf16 residual).
// EPI 1 (BN=128): V-transpose into vtp[b][d][t].
// EPI 2: masked exp scores + atomic rowsum.
// EPI 3: bf16 partial store (PV).
// ---------------------------------------------------------------------------
template <int BN, int EPI, int MODE, typename OutT>
__global__ __launch_bounds__(512, 2) void gemm8p(
    const bf16* __restrict__ A, const bf16* __restrict__ Bm,
    OutT* __restrict__ C, float* __restrict__ c2,
    const float* __restrict__ bias, const bf16* __restrict__ res,
    bf16* __restrict__ vtp, float* __restrict__ rowsum,
    int K, int lda, int ldb, int ldc, long sA, long sB, long sC)
{
    static_assert(EPI != 1 || BN == 128, "V-transpose epilogue needs BN=128");
    constexpr int BM = 256, BK = 32;
    constexpr int NT = BN / 64;                   // per-wave 16-col fragments
    constexpr int BUFE = (BM + BN) * BK;          // elems per buffer
    __shared__ __align__(16) bf16 smem[3 * BUFE];

    int bm, bn, bz = 0, chunk = 0;
    int kbeg = 0, kmax = K;
    if constexpr (MODE == 1) {
        bn = blockIdx.x; bz = blockIdx.y; bm = blockIdx.z;
        if (bn > bm) return;                       // causal block skip
    } else if constexpr (MODE == 2) {
        bn = blockIdx.x; bz = blockIdx.y;
        const int zc = blockIdx.z;
        bm = zbm_t[zc];
        chunk = zj_t[zc];
        kbeg = zk0_t[zc] * 64;
        kmax = zk1_t[zc] * 64;
    } else {
        bm = blockIdx.x; bn = blockIdx.y; bz = blockIdx.z;
    }
    const int NK = (kmax - kbeg) >> 5;             // K-tiles of 32

    const bf16* Ab = A + (size_t)bz * sA;
    const bf16* Bb = Bm + (size_t)bz * sB;

    const int tid = threadIdx.x;
    const int wave = tid >> 6;
    const int lane = tid & 63;
    const int wm = wave >> 2;          // 0..1  (M direction, 128 rows each)
    const int wn = wave & 3;           // 0..3  (N direction, BN/4 cols each)
    const int lr = lane >> 2;          // staging: row within 16-row subtile
    const int lc = ((lane & 3) ^ ((lane >> 5) << 1)) * 8;  // T2 pre-swizzled col
    const int arow = lane & 15;        // frag read: row within subtile
    const int kq = ((lane >> 4) * 8) ^ ((lane & 8) << 1);  // T2 swizzled k-offset

    const bf16* gA0 = Ab + (size_t)(bm * BM + wave * 16 + lr) * lda + lc + kbeg;
    const bf16* gA1 = Ab + (size_t)(bm * BM + (wave + 8) * 16 + lr) * lda + lc + kbeg;
    const bf16* gB0 = Bb + (size_t)(bn * BN + wave * 16 + lr) * ldb + lc + kbeg;
    const bf16* gB1 = (BN == 256)
        ? Bb + (size_t)(bn * BN + (wave + 8) * 16 + lr) * ldb + lc + kbeg : nullptr;

    f32x4 acc[8][NT] = {};

    // ---- prologue: stage tiles 0 and 1, wait for tile 0 only ----
    {
        bf16* As0 = smem;               // buf 0
        bf16* Bs0 = smem + BM * BK;
        bf16* As1 = smem + BUFE;        // buf 1
        bf16* Bs1 = smem + BUFE + BM * BK;
        async_copy16(gA0, As0 + wave * 512);
        async_copy16(gA1, As0 + (wave + 8) * 512);
        async_copy16(gB0, Bs0 + wave * 512);
        if constexpr (BN == 256) async_copy16(gB1, Bs0 + (wave + 8) * 512);
        async_copy16(gA0 + BK, As1 + wave * 512);
        async_copy16(gA1 + BK, As1 + (wave + 8) * 512);
        async_copy16(gB0 + BK, Bs1 + wave * 512);
        if constexpr (BN == 256) async_copy16(gB1 + BK, Bs1 + (wave + 8) * 512);
    }
    if constexpr (BN == 256) asm volatile("s_waitcnt vmcnt(4)" ::: "memory");
    else                     asm volatile("s_waitcnt vmcnt(3)" ::: "memory");
    __builtin_amdgcn_s_barrier();

    int cb = 0;  // buffer holding current tile kt
    int sb = 2;  // buffer receiving tile kt+2
    for (int kt = 0; kt < NK; ++kt) {
        const bf16* As = smem + cb * BUFE;
        const bf16* Bs = As + BM * BK;
        const bool st = (kt + 2) < NK;
        const int koff = (kt + 2) * BK;

        // ============ phase 1: low half of N fragments ============
        bf16x8 af[8], bf0[NT / 2];
#pragma unroll
        for (int mt = 0; mt < 8; ++mt)
            af[mt] = *(const bf16x8*)&As[(wm * 8 + mt) * 512 + arow * 32 + kq];
#pragma unroll
        for (int nt = 0; nt < NT / 2; ++nt)
            bf0[nt] = *(const bf16x8*)&Bs[(wn * NT + nt) * 512 + arow * 32 + kq];
        if (st) {  // stage A half of tile kt+2
            bf16* Ad = smem + sb * BUFE;
            async_copy16(gA0 + koff, Ad + wave * 512);
            async_copy16(gA1 + koff, Ad + (wave + 8) * 512);
        }
        __builtin_amdgcn_s_barrier();
        asm volatile("s_waitcnt lgkmcnt(0)" ::: "memory");
        __builtin_amdgcn_sched_barrier(0);
        __builtin_amdgcn_s_setprio(1);
#pragma unroll
        for (int mt = 0; mt < 8; ++mt)
#pragma unroll
            for (int nt = 0; nt < NT / 2; ++nt)
                acc[mt][nt] = __builtin_amdgcn_mfma_f32_16x16x32_bf16(
                    af[mt], bf0[nt], acc[mt][nt], 0, 0, 0);
        __builtin_amdgcn_s_setprio(0);
        __builtin_amdgcn_s_barrier();

        // ============ phase 2: high half of N fragments ============
        bf16x8 bf1[NT / 2];
#pragma unroll
        for (int nt = 0; nt < NT / 2; ++nt)
            bf1[nt] = *(const bf16x8*)&Bs[(wn * NT + NT / 2 + nt) * 512 + arow * 32 + kq];
        if (st) {  // stage B half of tile kt+2
            bf16* Bd = smem + sb * BUFE + BM * BK;
            async_copy16(gB0 + koff, Bd + wave * 512);
            if constexpr (BN == 256) async_copy16(gB1 + koff, Bd + (wave + 8) * 512);
        }
        __builtin_amdgcn_s_barrier();
        asm volatile("s_waitcnt lgkmcnt(0)" ::: "memory");
        __builtin_amdgcn_sched_barrier(0);
        __builtin_amdgcn_s_setprio(1);
#pragma unroll
        for (int mt = 0; mt < 8; ++mt)
#pragma unroll
            for (int nt = 0; nt < NT / 2; ++nt)
                acc[mt][NT / 2 + nt] = __builtin_amdgcn_mfma_f32_16x16x32_bf16(
                    af[mt], bf1[nt], acc[mt][NT / 2 + nt], 0, 0, 0);
        __builtin_amdgcn_s_setprio(0);
        if (st) {
            if constexpr (BN == 256) asm volatile("s_waitcnt vmcnt(4)" ::: "memory");
            else                     asm volatile("s_waitcnt vmcnt(3)" ::: "memory");
        } else {
            asm volatile("s_waitcnt vmcnt(0)" ::: "memory");
        }
        __builtin_amdgcn_s_barrier();

        cb = (cb + 1 == 3) ? 0 : cb + 1;
        sb = (sb + 1 == 3) ? 0 : sb + 1;
    }

    const int qrow = (lane >> 4) * 4;
    const int ccol = lane & 15;
    const int row0 = bm * BM + wm * 128;
    const int col0 = bn * BN + wn * (NT * 16);

    if constexpr (EPI == 1) {
        // V-transpose: block output is 256(t) x 128(d); write vt[b][d][t].
        bf16* tt = smem;
#pragma unroll
        for (int mt = 0; mt < 8; ++mt)
#pragma unroll
            for (int nt = 0; nt < NT; ++nt) {
                const int dl = wn * (NT * 16) + nt * 16 + ccol;
                const int tl = wm * 128 + mt * 16 + qrow;
                short4 o;
                o.x = f2bs(acc[mt][nt][0]);
                o.y = f2bs(acc[mt][nt][1]);
                o.z = f2bs(acc[mt][nt][2]);
                o.w = f2bs(acc[mt][nt][3]);
                *(short4*)&tt[dl * 264 + tl] = o;
            }
        __syncthreads();
        const int b = (bm * BM) >> 11;
        const int tin = (bm * BM) & (Tn - 1);
        const int dr = tid >> 4;           // 0..31
        const int t0 = (tid & 15) * 16;    // 0..240
#pragma unroll
        for (int p = 0; p < 4; ++p) {
            const int d = p * 32 + dr;
            const bf16* srcl = &tt[d * 264 + t0];
            bf16* dst = vtp + ((size_t)b * Dn + bn * BN + d) * Tn + tin + t0;
            ((bf16x8*)dst)[0] = ((const bf16x8*)srcl)[0];
            ((bf16x8*)dst)[1] = ((const bf16x8*)srcl)[1];
        }
        return;
    }

    if constexpr (EPI == 2) {
        // masked exp scores + atomic row sums (of the bf16-rounded values)
        OutT* Cb = C + (size_t)bz * sC;
        float* rsb = rowsum + (size_t)bz * Tn;
        const float scale = 0.03125f;
#pragma unroll
        for (int mt = 0; mt < 8; ++mt) {
            float rsv[4] = {0.f, 0.f, 0.f, 0.f};
#pragma unroll
            for (int nt = 0; nt < NT; ++nt) {
                const int cc = col0 + nt * 16 + ccol;
#pragma unroll
                for (int r = 0; r < 4; ++r) {
                    const int rr = row0 + mt * 16 + qrow + r;
                    float e = 0.0f;
                    if (cc <= rr) {
                        const short es = f2bs(__expf(acc[mt][nt][r] * scale));
                        Cb[(size_t)rr * ldc + cc] = *(const bf16*)&es;
                        e = b2f(es);
                    } else {
                        Cb[(size_t)rr * ldc + cc] = from_float<OutT>(0.0f);
                    }
                    rsv[r] += e;
                }
            }
#pragma unroll
            for (int r = 0; r < 4; ++r) {
                float v = rsv[r];
                v += __shfl_xor(v, 1);
                v += __shfl_xor(v, 2);
                v += __shfl_xor(v, 4);
                v += __shfl_xor(v, 8);
                if (ccol == 0)
                    atomicAdd(rsb + row0 + mt * 16 + qrow + r, v);
            }
        }
        return;
    }

    if constexpr (EPI == 3) {
        // bf16 partial store (PV split-K): partial j -> {C, c2, vtp}
        bf16* Cb;
        if (chunk == 0)      Cb = (bf16*)C;
        else if (chunk == 1) Cb = (bf16*)c2;
        else                 Cb = vtp;
        Cb += (size_t)bz * sC;
#pragma unroll
        for (int mt = 0; mt < 8; ++mt)
#pragma unroll
            for (int nt = 0; nt < NT; ++nt) {
                const int cc = col0 + nt * 16 + ccol;
#pragma unroll
                for (int r = 0; r < 4; ++r) {
                    const int rr = row0 + mt * 16 + qrow + r;
                    Cb[(size_t)rr * ldc + cc] = f2b(acc[mt][nt][r]);
                }
            }
        return;
    }

    // EPI 0: plain epilogue (+bias, optional bf16 residual)
#pragma unroll
    for (int mt = 0; mt < 8; ++mt)
#pragma unroll
        for (int nt = 0; nt < NT; ++nt) {
            const int cc = col0 + nt * 16 + ccol;
            const float bv = bias ? bias[cc] : 0.0f;
#pragma unroll
            for (int r = 0; r < 4; ++r) {
                const int rr = row0 + mt * 16 + qrow + r;
                float v = acc[mt][nt][r] + bv;
                if (res) v += b2f(*(const short*)&res[(size_t)rr * ldc + cc]);
                C[(size_t)rr * ldc + cc] = from_float<OutT>(v);
            }
        }
}

// ---------------------------------------------------------------------------
// Generic NT GEMM (2-barrier 128x128 structure) — MLP1/MLP2 only.
// T2 swizzle applied (conflict-free reads).
// ---------------------------------------------------------------------------
template <int BM, int BN, int MINW, int EPI, typename OutT, typename ResT, bool RELU>
__global__ __launch_bounds__(256, MINW) void gemm_nt(
    const bf16* __restrict__ A, const bf16* __restrict__ Bm,
    OutT* __restrict__ C, const float* __restrict__ bias,
    const ResT* __restrict__ res,
    int M, int N, int K, int lda, int ldb, int ldc)
{
    const int bm = blockIdx.x, bn = blockIdx.y;

    constexpr int WROWS = BM / 64;
    constexpr int WCOLS = 4 / WROWS;
    constexpr int TM = 64;
    constexpr int TN = BN / WCOLS;
    constexpr int MT = TM / 16;
    constexpr int NT = TN / 16;
    constexpr int nA = BM / 16;
    constexpr int nB = BN / 16;
    constexpr int STAGE = 2 * (BM + BN) * 32;

    __shared__ __align__(16) bf16 smem[STAGE];
    bf16* As = smem;
    bf16* Bs = smem + 2 * BM * 32;

    const int tid = threadIdx.x;
    const int wave = tid >> 6;
    const int lane = tid & 63;
    const int wm = wave / WCOLS;
    const int wn = wave % WCOLS;

    f32x4 acc[MT][NT] = {};

    const int lr = lane >> 2;
    const int lc = ((lane & 3) ^ ((lane >> 5) << 1)) * 8;  // T2 pre-swizzled col
    const bf16* gAc[nA / 4]; bf16* lAc[nA / 4];
    const bf16* gBc[nB / 4]; bf16* lBc[nB / 4];
#pragma unroll
    for (int i = 0; i < nA / 4; ++i) {
        const int c = wave + 4 * i;
        gAc[i] = A + (size_t)(bm * BM + c * 16 + lr) * lda + lc;
        lAc[i] = &As[c * 512];
    }
#pragma unroll
    for (int i = 0; i < nB / 4; ++i) {
        const int c = wave + 4 * i;
        gBc[i] = Bm + (size_t)(bn * BN + c * 16 + lr) * ldb + lc;
        lBc[i] = &Bs[c * 512];
    }

    const int arow = lane & 15;
    const int kq = ((lane >> 4) * 8) ^ ((lane & 8) << 1);  // T2 swizzled k-offset

    for (int k0 = 0; k0 < K; k0 += 64) {
#pragma unroll
        for (int hh = 0; hh < 2; ++hh) {
#pragma unroll
            for (int i = 0; i < nA / 4; ++i)
                async_copy16(gAc[i] + k0 + 32 * hh, lAc[i] + hh * (BM * 32));
#pragma unroll
            for (int i = 0; i < nB / 4; ++i)
                async_copy16(gBc[i] + k0 + 32 * hh, lBc[i] + hh * (BN * 32));
        }
        __syncthreads();

#pragma unroll
        for (int hh = 0; hh < 2; ++hh) {
            const bf16* Ah = As + hh * (BM * 32);
            const bf16* Bh = Bs + hh * (BN * 32);
            bf16x8 af[MT], bfm[NT];
#pragma unroll
            for (int t = 0; t < MT; ++t)
                af[t] = *(const bf16x8*)&Ah[(wm * TM + t * 16 + arow) * 32 + kq];
#pragma unroll
            for (int t = 0; t < NT; ++t)
                bfm[t] = *(const bf16x8*)&Bh[(wn * TN + t * 16 + arow) * 32 + kq];
#pragma unroll
            for (int mt = 0; mt < MT; ++mt)
#pragma unroll
                for (int nt = 0; nt < NT; ++nt)
                    acc[mt][nt] = __builtin_amdgcn_mfma_f32_16x16x32_bf16(
                        af[mt], bfm[nt], acc[mt][nt], 0, 0, 0);
        }
        __syncthreads();
    }

    const int rowBase = bm * BM + wm * TM;
    const int colBase = bn * BN + wn * TN;
    const int qrow = (lane >> 4) * 4;
    const int ccol = lane & 15;

#pragma unroll
    for (int mt = 0; mt < MT; ++mt) {
#pragma unroll
        for (int nt = 0; nt < NT; ++nt) {
            const int cc = colBase + nt * 16 + ccol;
            const float bv = bias ? bias[cc] : 0.0f;
#pragma unroll
            for (int r = 0; r < 4; ++r) {
                const int rr = rowBase + mt * 16 + qrow + r;
                float v = acc[mt][nt][r] + bv;
                if (RELU) v = fmaxf(v, 0.0f);
                if (res) v += ldf(res[(size_t)rr * ldc + cc]);
                C[(size_t)rr * ldc + cc] = from_float<OutT>(v);
            }
        }
    }
}

// ---------------------------------------------------------------------------
// LayerNorm body (faithfully buggy): out = (x - mean/sqrt(var_unbiased))*g + b
// ---------------------------------------------------------------------------
template <typename InT>
__device__ __forceinline__ void ln_row(
    const InT* __restrict__ xr, const float* __restrict__ gamma,
    const float* __restrict__ beta, bf16* __restrict__ orow, int tid)
{
    const int j = tid * 4;
    float v[4];
    load4(xr + j, v);
    float s = v[0] + v[1] + v[2] + v[3];
    float sq = v[0] * v[0] + v[1] * v[1] + v[2] * v[2] + v[3] * v[3];
#pragma unroll
    for (int o = 32; o > 0; o >>= 1) {
        s += __shfl_down(s, o);
        sq += __shfl_down(sq, o);
    }
    __shared__ float red[2][4];
    const int lane = tid & 63, w = tid >> 6;
    if (lane == 0) { red[0][w] = s; red[1][w] = sq; }
    __syncthreads();
    s  = red[0][0] + red[0][1] + red[0][2] + red[0][3];
    sq = red[1][0] + red[1][1] + red[1][2] + red[1][3];
    const float mean = s / (float)Dn;
    const float var = (sq - s * s / (float)Dn) / (float)(Dn - 1);
    const float coef = mean * rsqrtf(var);

    const float4 g = *(const float4*)(gamma + j);
    const float4 be = *(const float4*)(beta + j);
    short4 o;
    o.x = f2bs((v[0] - coef) * g.x + be.x);
    o.y = f2bs((v[1] - coef) * g.y + be.y);
    o.z = f2bs((v[2] - coef) * g.z + be.z);
    o.w = f2bs((v[3] - coef) * g.w + be.w);
    *(short4*)(orow + j) = o;
}

// ---------------------------------------------------------------------------
// Fused PV-merge + LN2: y = (p0 [+ p1 [+ p2]])/rowsum + x (fp32), write y
// (bf16) and h2 = LN(y). Partial count per row-block: {1,1,2,2,2,2,3,3}.
// ---------------------------------------------------------------------------
__global__ __launch_bounds__(256) void ln2_fused(
    const bf16* __restrict__ yp0, const bf16* __restrict__ yp1,
    const bf16* __restrict__ yp2,
    const float* __restrict__ rowsum, const float* __restrict__ x,
    const float* __restrict__ gamma, const float* __restrict__ beta,
    bf16* __restrict__ y, bf16* __restrict__ h2)
{
    const int row = blockIdx.x;
    const int tid = threadIdx.x;
    const int j = tid * 4;
    const size_t base = (size_t)row * Dn;
    const float inv = 1.0f / rowsum[row];

    const int bmrow = (row & (Tn - 1)) >> 8;      // row-block within batch
    const int nch = (bmrow < 2) ? 1 : (bmrow < 6 ? 2 : 3);

    float p[4], xv[4], v[4];
    load4(yp0 + base + j, p);
    if (nch > 1) {
        float q[4];
        load4(yp1 + base + j, q);
        p[0] += q[0]; p[1] += q[1]; p[2] += q[2]; p[3] += q[3];
    }
    if (nch > 2) {
        float q[4];
        load4(yp2 + base + j, q);
        p[0] += q[0]; p[1] += q[1]; p[2] += q[2]; p[3] += q[3];
    }
    load4(x + base + j, xv);
    short4 yo;
    v[0] = p[0] * inv + xv[0];
    v[1] = p[1] * inv + xv[1];
    v[2] = p[2] * inv + xv[2];
    v[3] = p[3] * inv + xv[3];
    yo.x = f2bs(v[0]); yo.y = f2bs(v[1]); yo.z = f2bs(v[2]); yo.w = f2bs(v[3]);
    *(short4*)(y + base + j) = yo;

    float s = v[0] + v[1] + v[2] + v[3];
    float sq = v[0] * v[0] + v[1] * v[1] + v[2] * v[2] + v[3] * v[3];
#pragma unroll
    for (int o = 32; o > 0; o >>= 1) {
        s += __shfl_down(s, o);
        sq += __shfl_down(sq, o);
    }
    __shared__ float red[2][4];
    const int lane = tid & 63, w = tid >> 6;
    if (lane == 0) { red[0][w] = s; red[1][w] = sq; }
    __syncthreads();
    s  = red[0][0] + red[0][1] + red[0][2] + red[0][3];
    sq = red[1][0] + red[1][1] + red[1][2] + red[1][3];
    const float mean = s / (float)Dn;
    const float var = (sq - s * s / (float)Dn) / (float)(Dn - 1);
    const float coef = mean * rsqrtf(var);

    const float4 g = *(const float4*)(gamma + j);
    const float4 be = *(const float4*)(beta + j);
    short4 o;
    o.x = f2bs((v[0] - coef) * g.x + be.x);
    o.y = f2bs((v[1] - coef) * g.y + be.y);
    o.z = f2bs((v[2] - coef) * g.z + be.z);
    o.w = f2bs((v[3] - coef) * g.w + be.w);
    *(short4*)(h2 + base + j) = o;
}

// ---------------------------------------------------------------------------
// Fused prep: [0,5120) weight transposes (5 x 1024^2, fp32->bf16),
// [5120,5128) zero rowsum, [5128,13320) LN1 rows.
// ---------------------------------------------------------------------------
struct WPtrs { const float* p[5]; };

__global__ __launch_bounds__(256) void prep_kernel(
    WPtrs wp, bf16* __restrict__ wdst, float* __restrict__ rowsum,
    const float* __restrict__ x, const float* __restrict__ gamma1,
    const float* __restrict__ beta1, bf16* __restrict__ h)
{
    const int bx = blockIdx.x;
    if (bx < 5120) {
        __shared__ bf16 tile[32][33];
        const int z = bx >> 10;
        const int t = bx & 1023;
        const float* src = wp.p[z];
        bf16* d = wdst + (size_t)z * Dn * Dn;
        const int c0 = (t & 31) * 32, r0 = (t >> 5) * 32;
        const int tx = threadIdx.x & 31;
        const int ty = threadIdx.x >> 5;
#pragma unroll
        for (int dy = 0; dy < 32; dy += 8)
            tile[ty + dy][tx] = f2b(src[(size_t)(r0 + ty + dy) * Dn + (c0 + tx)]);
        __syncthreads();
#pragma unroll
        for (int dy = 0; dy < 32; dy += 8)
            d[(size_t)(c0 + ty + dy) * Dn + (r0 + tx)] = tile[tx][ty + dy];
    } else if (bx < 5128) {
        const int base = (bx - 5120) * 1024;
#pragma unroll
        for (int i = 0; i < 4; ++i) rowsum[base + i * 256 + threadIdx.x] = 0.0f;
    } else {
        const int row = bx - 5128;
        ln_row(x + (size_t)row * Dn, gamma1, beta1, h + (size_t)row * Dn, threadIdx.x);
    }
}

extern "C" void kernel_launch(void* const* d_in, const int* in_sizes, int n_in,
                              void* d_out, int out_size, void* d_ws, size_t ws_size,
                              hipStream_t stream) {
    const float* x      = (const float*)d_in[0];
    const float* gamma1 = (const float*)d_in[1];
    const float* beta1  = (const float*)d_in[2];
    const float* w_q    = (const float*)d_in[3];
    const float* w_k    = (const float*)d_in[4];
    const float* w_v    = (const float*)d_in[5];
    const float* gamma2 = (const float*)d_in[6];
    const float* beta2  = (const float*)d_in[7];
    const float* W1     = (const float*)d_in[8];
    const float* b1     = (const float*)d_in[9];
    const float* W2     = (const float*)d_in[10];
    const float* b2     = (const float*)d_in[11];
    float* out = (float*)d_out;   // fp32 output buffer (compared in bf16 space)

    char* ws = (char*)d_ws;
    size_t off = 0;
    auto alloc = [&](size_t bytes) {
        char* p = ws + off;
        off += (bytes + 255) & ~(size_t)255;
        return p;
    };
    const size_t BT = (size_t)Bn * Tn;
    bf16* h    = (bf16*)alloc(BT * Dn * 2);               // 16 MB; reused as h2
    bf16* qk   = (bf16*)alloc(BT * 2 * Dn * 2);           // 32 MB [8192,2048] (q|k)
    bf16* vt   = (bf16*)alloc(BT * Dn * 2);               // 16 MB [4][1024,2048]
    bf16* wbuf = (bf16*)alloc((size_t)5 * Dn * Dn * 2);   // 10 MB (wq|wk|wv|w1|w2)^T
    bf16* S    = (bf16*)alloc((size_t)Bn * Tn * Tn * 2);  // 32 MB masked exp scores
    bf16* y    = (bf16*)alloc(BT * Dn * 2);               // 16 MB
    float* rowsum = (float*)alloc((size_t)Bn * Tn * 4);   // 32 KB
    bf16* yp12 = (bf16*)alloc(BT * Dn * 2 * 2);           // 32 MB: yp1|yp2 bf16
    bf16* yp0 = (bf16*)qk;     // 16 MB partial 0 — qk dead after scores
    bf16* yp1 = yp12;
    bf16* yp2 = yp12 + BT * Dn;
    bf16* h2   = h;            // h dead after QKV
    bf16* mid  = qk;           // qk dead after ln2_fused consumed yp0

    const dim3 blk(256);
    const dim3 blk512(512);
    const long TD  = (long)Tn * Dn;
    const long TT  = (long)Tn * Tn;
    const long TD2 = (long)Tn * 2 * Dn;
    const size_t DD = (size_t)Dn * Dn;

    // fused: 5 weight transposes + rowsum zero + LN1
    WPtrs wp; wp.p[0] = w_q; wp.p[1] = w_k; wp.p[2] = w_v; wp.p[3] = W1; wp.p[4] = W2;
    prep_kernel<<<dim3(5128 + (unsigned)BT, 1, 1), blk, 0, stream>>>(
        wp, wbuf, rowsum, x, gamma1, beta1, h);

    // qk = h @ [wq|wk]^T : 8-phase 256^2, grid 32x8 = 256 blocks (1/CU)
    gemm8p<256, 0, 0, bf16><<<dim3(32, 8, 1), blk512, 0, stream>>>(
        h, wbuf, qk, nullptr, nullptr, nullptr, nullptr, nullptr,
        Dn, Dn, Dn, 2 * Dn, 0, 0, 0);

    // vt[b][d][t] = (h @ wv^T)^T : 8-phase 256x128 + LDS-transpose epilogue
    gemm8p<128, 1, 0, bf16><<<dim3(32, 8, 1), blk512, 0, stream>>>(
        h, wbuf + 2 * DD, (bf16*)nullptr, nullptr, nullptr, nullptr, vt, nullptr,
        Dn, Dn, Dn, 0, 0, 0, 0);

    // S_exp = exp(q @ k^T * scale) causal-masked + atomic rowsum
    // 8-phase 256^2, grid (bn=8, bz=4, bm=8), 144 live blocks
    gemm8p<256, 2, 1, bf16><<<dim3(8, Bn, 8), blk512, 0, stream>>>(
        qk, qk + 1024, S, nullptr, nullptr, nullptr, nullptr, rowsum,
        Dn, 2 * Dn, 2 * Dn, Tn, TD2, TD2, TT);

    // PV split-K (rebalanced, max chunk K=768): bf16 partials 0/1/2 ->
    // yp0 (over qk) / yp1 / yp2; grid (bn=4, bz=4, zc=16) = 256 blocks
    gemm8p<256, 3, 2, bf16><<<dim3(4, Bn, 16), blk512, 0, stream>>>(
        S, vt, yp0, (float*)yp1, nullptr, nullptr, yp2, nullptr,
        Tn, Tn, Tn, Dn, TT, TD, TD);

    // fused merge + LN2: y = (yp0[+yp1[+yp2]])/rowsum + x ; h2 = LN(y)
    ln2_fused<<<dim3((unsigned)BT), blk, 0, stream>>>(
        yp0, yp1, yp2, rowsum, x, gamma2, beta2, y, h2);

    // mid = relu(h2 @ W1 + b1)
    gemm_nt<128, 128, 4, 0, bf16, float, true><<<dim3(64, 8, 1), blk, 0, stream>>>(
        h2, wbuf + 3 * DD, mid, b1, nullptr,
        (int)BT, Dn, Dn, Dn, Dn, Dn);

    // out = mid @ W2 + b2 + y (fp32 out, bf16 residual)
    gemm_nt<128, 128, 4, 0, float, bf16, false><<<dim3(64, 8, 1), blk, 0, stream>>>(
        mid, wbuf + 4 * DD, out, b2, y,
        (int)BT, Dn, Dn, Dn, Dn, Dn);
}